// Round 1
// baseline (374.047 us; speedup 1.0000x reference)
//
#include <hip/hip_runtime.h>
#include <hip/hip_bf16.h>
#include <stdint.h>

// Problem constants (fixed by the reference file)
#define NB 8     // batch
#define NS 2048  // sequence
#define ND 1536  // model dim (K)
#define NT 2048  // padded tracks (N)
#define NH 8     // heads

// NUM_TRACKS = [128,256,512,1024,2048,64,32,1024] -> ceil(nt/128)*128
__constant__ int c_nlim[NH] = {128, 256, 512, 1024, 2048, 128, 128, 1024};

typedef short bf16x8 __attribute__((ext_vector_type(8)));  // 8 bf16 (4 VGPRs)
typedef float f32x4 __attribute__((ext_vector_type(4)));

__device__ __forceinline__ unsigned short f2bf(float f) {
    union { float f; unsigned u; } a; a.f = f;
    unsigned r = a.u + 0x7fffu + ((a.u >> 16) & 1u);  // RNE
    return (unsigned short)(r >> 16);
}

// ---------------- Prepass 1: x fp32 -> bf16 ----------------
__global__ void cvt_x_kernel(const float* __restrict__ x,
                             unsigned short* __restrict__ xb) {
    const size_t i = (size_t)blockIdx.x * 256 + threadIdx.x;  // float4 index
    float4 v = ((const float4*)x)[i];
    ushort4 o;
    o.x = f2bf(v.x); o.y = f2bf(v.y); o.z = f2bf(v.z); o.w = f2bf(v.w);
    ((ushort4*)xb)[i] = o;
}

// ---------------- Prepass 2: W[h][d][t] fp32 -> Wt[h][t][d] bf16 ----------
// Only heads present in head_idx, only t < c_nlim[h].
__global__ void cvt_w_kernel(const float* __restrict__ W,
                             const int* __restrict__ hidx,
                             unsigned short* __restrict__ Wt) {
    const int h = blockIdx.z;
    bool used = false;
    for (int i = 0; i < NB; ++i) used |= (hidx[i] == h);
    if (!used) return;
    const int t0 = blockIdx.x * 32;
    if (t0 >= c_nlim[h]) return;
    const int d0 = blockIdx.y * 32;

    __shared__ float tile[32][33];
    const int tx = threadIdx.x, ty = threadIdx.y;
#pragma unroll
    for (int i = 0; i < 4; ++i) {
        const int d = d0 + ty + i * 8;
        tile[ty + i * 8][tx] = W[((size_t)h * ND + d) * NT + t0 + tx];
    }
    __syncthreads();
#pragma unroll
    for (int i = 0; i < 4; ++i) {
        const int t = t0 + ty + i * 8;
        Wt[((size_t)h * NT + t) * ND + d0 + tx] = f2bf(tile[tx][ty + i * 8]);
    }
}

// ---------------- GEMM: out[b] = x[b] @ W[h(b)] + bias[h(b)] ----------------
// m97 structure: 128x128 tile, BK=32, 4 waves of 64x64, 16x16x32 bf16 MFMA,
// global_load_lds width=16, contiguous LDS layout, 2 barriers per K-iter.
#define GLDS(g, l)                                                      \
    __builtin_amdgcn_global_load_lds(                                   \
        (const __attribute__((address_space(1))) void*)(g),             \
        (__attribute__((address_space(3))) void*)(l), 16, 0, 0)

__global__ __launch_bounds__(256) void gemm_kernel(
    const unsigned short* __restrict__ xb,   // bf16 [NB][NS][ND]
    const unsigned short* __restrict__ wt,   // bf16 [NH][NT][ND]
    const float* __restrict__ bias,          // fp32 [NH][NT]
    const int* __restrict__ hidx,            // [NB]
    float* __restrict__ out)                 // fp32 [NB][NS][NT]
{
    const int batch = blockIdx.z;
    const int m0 = blockIdx.y * 128;
    const int n0 = blockIdx.x * 128;
    const int h = hidx[batch];
    const int tid = threadIdx.x;
    float* outb = out + (size_t)batch * NS * NT;

    if (n0 >= c_nlim[h]) {
        // Pure zero tile: W and bias are exactly zero here -> logits == 0.
        const int row = tid >> 1;
        const int c0 = (tid & 1) * 64;
        float4 z = make_float4(0.f, 0.f, 0.f, 0.f);
        float4* p = (float4*)(outb + (size_t)(m0 + row) * NT + (n0 + c0));
#pragma unroll
        for (int j = 0; j < 16; ++j) p[j] = z;
        return;
    }

    __shared__ unsigned short As[128 * 32];  // [m][k] row-major
    __shared__ unsigned short Bs[128 * 32];  // [n][k] row-major (B^T)

    const int lane = tid & 63;
    const int wave = tid >> 6;
    const int wm = (wave >> 1) * 64;
    const int wn = (wave & 1) * 64;
    const int fr = lane & 15;        // m (A) / n (B) / col (C)
    const int fq = (lane >> 4) * 8;  // k-group

    // Staging: 512 16B-chunks per tile; thread handles chunks tid and tid+256.
    const int r0 = tid >> 2, kc0 = (tid & 3) * 8;
    const int i1 = tid + 256;
    const int r1 = i1 >> 2, kc1 = (i1 & 3) * 8;

    const unsigned short* ga0 = xb + ((size_t)batch * NS + m0 + r0) * ND + kc0;
    const unsigned short* ga1 = xb + ((size_t)batch * NS + m0 + r1) * ND + kc1;
    const unsigned short* gb0 = wt + ((size_t)h * NT + n0 + r0) * ND + kc0;
    const unsigned short* gb1 = wt + ((size_t)h * NT + n0 + r1) * ND + kc1;
    unsigned short* la0 = As + tid * 8;
    unsigned short* la1 = As + i1 * 8;
    unsigned short* lb0 = Bs + tid * 8;
    unsigned short* lb1 = Bs + i1 * 8;

    f32x4 acc[4][4] = {};

    for (int k0 = 0; k0 < ND; k0 += 32) {
        GLDS(ga0, la0); GLDS(ga1, la1); GLDS(gb0, lb0); GLDS(gb1, lb1);
        __syncthreads();  // drains vmcnt (compiler emits full waitcnt)
        bf16x8 af[4], bfr[4];
#pragma unroll
        for (int mi = 0; mi < 4; ++mi)
            af[mi] = *(const bf16x8*)(As + (wm + mi * 16 + fr) * 32 + fq);
#pragma unroll
        for (int ni = 0; ni < 4; ++ni)
            bfr[ni] = *(const bf16x8*)(Bs + (wn + ni * 16 + fr) * 32 + fq);
#pragma unroll
        for (int mi = 0; mi < 4; ++mi)
#pragma unroll
            for (int ni = 0; ni < 4; ++ni)
                acc[mi][ni] = __builtin_amdgcn_mfma_f32_16x16x32_bf16(
                    af[mi], bfr[ni], acc[mi][ni], 0, 0, 0);
        __syncthreads();
        ga0 += 32; ga1 += 32; gb0 += 32; gb1 += 32;
    }

    // Epilogue: C/D layout col=lane&15, row=(lane>>4)*4+reg
    float bv[4];
#pragma unroll
    for (int ni = 0; ni < 4; ++ni)
        bv[ni] = bias[(size_t)h * NT + n0 + wn + ni * 16 + fr];

    const int rbase = m0 + wm + (lane >> 4) * 4;
#pragma unroll
    for (int mi = 0; mi < 4; ++mi) {
#pragma unroll
        for (int r = 0; r < 4; ++r) {
            float* op = outb + (size_t)(rbase + mi * 16 + r) * NT + n0 + wn + fr;
#pragma unroll
            for (int ni = 0; ni < 4; ++ni)
                op[ni * 16] = acc[mi][ni][r] + bv[ni];
        }
    }
}

extern "C" void kernel_launch(void* const* d_in, const int* in_sizes, int n_in,
                              void* d_out, int out_size, void* d_ws, size_t ws_size,
                              hipStream_t stream) {
    const float* x    = (const float*)d_in[0];  // [NB][NS][ND] fp32
    const int*   hidx = (const int*)d_in[1];    // [NB] int32
    const float* W    = (const float*)d_in[2];  // [NH][ND][NT] fp32
    const float* bias = (const float*)d_in[3];  // [NH][NT] fp32
    float* out = (float*)d_out;

    unsigned short* xb = (unsigned short*)d_ws;            // 48 MiB bf16 x
    unsigned short* wt = xb + (size_t)NB * NS * ND;        // 48 MiB bf16 W^T

    // x convert: 25165824 floats = 6291456 float4s / 256 = 24576 blocks
    cvt_x_kernel<<<dim3(24576), dim3(256), 0, stream>>>(x, xb);
    // W transpose+convert: (T/32, D/32, H)
    cvt_w_kernel<<<dim3(NT / 32, ND / 32, NH), dim3(32, 8), 0, stream>>>(W, hidx, wt);
    // GEMM: (N/128, M/128, B)
    gemm_kernel<<<dim3(NT / 128, NS / 128, NB), dim3(256), 0, stream>>>(
        xb, wt, bias, hidx, out);
}